// Round 1
// baseline (541.090 us; speedup 1.0000x reference)
//
#include <hip/hip_runtime.h>
#include <hip/hip_bf16.h>
#include <math.h>

#define DD 768
#define HH 3072
#define EE 8
#define NN 2048   // B*T tokens
#define MM 4096   // NN * K(=2) compact rows

typedef __attribute__((ext_vector_type(8))) short short8;   // 8 bf16 (4 VGPRs) MFMA operand
typedef __attribute__((ext_vector_type(4))) float floatx4;  // MFMA accumulator

__device__ __forceinline__ unsigned short f2bf(float f) {
    union { float f; unsigned int u; } v; v.f = f;
    unsigned int u = v.u;
    u += 0x7fffu + ((u >> 16) & 1u);   // RNE (inputs finite)
    return (unsigned short)(u >> 16);
}

// ---------------------------------------------------------------------------
// 1. Routing: z3 = x.Wr^T ; logits = z3.dirs^T ; softmax ; top-2 ; gates
// ---------------------------------------------------------------------------
__global__ __launch_bounds__(256) void routing_kernel(
    const float* __restrict__ x, const float* __restrict__ Wr,
    int* __restrict__ counts, float* __restrict__ psum,
    int* __restrict__ top_e, float* __restrict__ top_g)
{
    __shared__ float wr[3 * DD];
    __shared__ float lpsum[EE];
    int tid = threadIdx.x;
    for (int i = tid; i < 3 * DD; i += 256) wr[i] = Wr[i];
    if (tid < EE) lpsum[tid] = 0.f;
    __syncthreads();

    int n = blockIdx.x * 256 + tid;   // grid = 8 blocks -> n < 2048 always
    const float4* xp = (const float4*)(x + (size_t)n * DD);
    float z0 = 0.f, z1 = 0.f, z2 = 0.f;
#pragma unroll 8
    for (int i = 0; i < DD / 4; i++) {
        float4 v = xp[i];
        int d = i * 4;
        z0 = fmaf(v.x, wr[d], z0);         z0 = fmaf(v.y, wr[d+1], z0);
        z0 = fmaf(v.z, wr[d+2], z0);       z0 = fmaf(v.w, wr[d+3], z0);
        z1 = fmaf(v.x, wr[DD+d], z1);      z1 = fmaf(v.y, wr[DD+d+1], z1);
        z1 = fmaf(v.z, wr[DD+d+2], z1);    z1 = fmaf(v.w, wr[DD+d+3], z1);
        z2 = fmaf(v.x, wr[2*DD+d], z2);    z2 = fmaf(v.y, wr[2*DD+d+1], z2);
        z2 = fmaf(v.z, wr[2*DD+d+2], z2);  z2 = fmaf(v.w, wr[2*DD+d+3], z2);
    }

    const float r3 = 0.57735026918962576f; // 1/sqrt(3)
    float p[EE];
    float mx = -1e30f;
#pragma unroll
    for (int e = 0; e < EE; e++) {
        float s0 = (e & 4) ? z0 : -z0;   // itertools.product([-1,1]) order
        float s1 = (e & 2) ? z1 : -z1;
        float s2 = (e & 1) ? z2 : -z2;
        p[e] = (s0 + s1 + s2) * r3;
        mx = fmaxf(mx, p[e]);
    }
    float sum = 0.f;
#pragma unroll
    for (int e = 0; e < EE; e++) { p[e] = expf(p[e] - mx); sum += p[e]; }
    float inv_s = 1.f / sum;
#pragma unroll
    for (int e = 0; e < EE; e++) p[e] *= inv_s;   // probs

    // top-2, lower index wins ties (strict >)
    int e1 = 0; float p1 = p[0];
#pragma unroll
    for (int e = 1; e < EE; e++) if (p[e] > p1) { p1 = p[e]; e1 = e; }
    int e2 = -1; float p2 = -1.f;
#pragma unroll
    for (int e = 0; e < EE; e++) if (e != e1 && p[e] > p2) { p2 = p[e]; e2 = e; }
    float inv_t = 1.f / (p1 + p2);
    top_e[2*n]   = e1;  top_g[2*n]   = p1 * inv_t;
    top_e[2*n+1] = e2;  top_g[2*n+1] = p2 * inv_t;
    atomicAdd(&counts[e1], 1);
    atomicAdd(&counts[e2], 1);

#pragma unroll
    for (int e = 0; e < EE; e++) atomicAdd(&lpsum[e], p[e]);
    __syncthreads();
    if (tid < EE) atomicAdd(&psum[tid], lpsum[tid]);
}

// ---------------------------------------------------------------------------
// 2. Scan counts -> offsets (cursor), aux loss
// ---------------------------------------------------------------------------
__global__ void scan_aux_kernel(int* __restrict__ counts, const float* __restrict__ psum,
                                int* __restrict__ offs, float* __restrict__ out_aux)
{
    if (threadIdx.x == 0) {
        int run = 0;
        for (int e = 0; e < EE; e++) { offs[e] = run; run += counts[e]; }
        offs[EE] = run;
        for (int e = 0; e < EE; e++) counts[e] = offs[e]; // becomes cursor
        float s = 0.f;
        for (int e = 0; e < EE; e++) {
            float t = psum[e] * (1.f / NN) - (1.f / EE);
            s += t * t;
        }
        *out_aux = 0.01f * (s * (1.f / EE));
    }
}

// ---------------------------------------------------------------------------
// 3. Scatter tokens into compact per-expert rows
// ---------------------------------------------------------------------------
__global__ __launch_bounds__(256) void scatter_kernel(
    const int* __restrict__ top_e, const float* __restrict__ top_g,
    int* __restrict__ cursor, int* __restrict__ row_tok, float* __restrict__ row_gate)
{
    int n = blockIdx.x * 256 + threadIdx.x;
#pragma unroll
    for (int k = 0; k < 2; k++) {
        int e = top_e[2*n + k];
        int pos = atomicAdd(&cursor[e], 1);
        row_tok[pos]  = n;
        row_gate[pos] = top_g[2*n + k];
    }
}

// ---------------------------------------------------------------------------
// 4. Weight transpose + bf16 cast: W1(E,D,H)->w1t(E,H,D), W2(E,H,D)->w2t(E,D,H)
// ---------------------------------------------------------------------------
__global__ __launch_bounds__(256) void transpose_cast_kernel(
    const float* __restrict__ W1, const float* __restrict__ W2,
    unsigned short* __restrict__ w1t, unsigned short* __restrict__ w2t)
{
    int z = blockIdx.z, e = blockIdx.y, bx = blockIdx.x;
    const float* src; unsigned short* dst; int R, C, rt, ct;
    if (z == 0) { R = DD; C = HH; src = W1 + (size_t)e * R * C; dst = w1t + (size_t)e * R * C; }
    else        { R = HH; C = DD; src = W2 + (size_t)e * R * C; dst = w2t + (size_t)e * R * C; }
    rt = bx / (C / 64); ct = bx % (C / 64);
    int r0 = rt * 64, c0 = ct * 64;

    __shared__ unsigned short tile[64][66];
    int tid = threadIdx.x;
    int lr = tid >> 2, lc = (tid & 3) * 16;
    const float4* sp = (const float4*)(src + (size_t)(r0 + lr) * C + c0 + lc);
#pragma unroll
    for (int j = 0; j < 4; j++) {
        float4 v = sp[j];
        tile[lr][lc + 4*j + 0] = f2bf(v.x);
        tile[lr][lc + 4*j + 1] = f2bf(v.y);
        tile[lr][lc + 4*j + 2] = f2bf(v.z);
        tile[lr][lc + 4*j + 3] = f2bf(v.w);
    }
    __syncthreads();
    int oc = tid >> 2, orr = (tid & 3) * 16;
    alignas(16) unsigned short tmp[16];
#pragma unroll
    for (int j = 0; j < 16; j++) tmp[j] = tile[orr + j][oc];
    unsigned short* dp = dst + (size_t)(c0 + oc) * R + r0 + orr;
    *(uint4*)dp       = *(uint4*)&tmp[0];
    *(uint4*)(dp + 8) = *(uint4*)&tmp[8];
}

// ---------------------------------------------------------------------------
// 5. GEMM1: h = gelu(x_gathered @ W1[e]) -> bf16   (M=cnt_e, K=768, N=3072)
// ---------------------------------------------------------------------------
__global__ __launch_bounds__(256, 2) void gemm1_kernel(
    const float* __restrict__ x, const unsigned short* __restrict__ w1t,
    unsigned short* __restrict__ h, const int* __restrict__ offs,
    const int* __restrict__ row_tok)
{
    int e = blockIdx.x >> 4, mt = blockIdx.x & 15;
    int base = offs[e], cnt = offs[e + 1] - base;
    if (mt * 128 >= cnt) return;
    int row0 = base + mt * 128;
    int mrem = cnt - mt * 128; if (mrem > 128) mrem = 128;

    __shared__ alignas(16) unsigned short As[128][40];
    __shared__ alignas(16) unsigned short Bs[128][40];

    int tid = threadIdx.x;
    int wave = tid >> 6, lane = tid & 63;
    int quad = lane >> 4, l15 = lane & 15;
    int wm = (wave & 1) * 64, wn = (wave >> 1) * 64;
    int srow = tid >> 1, shalf = (tid & 1) * 16;

    int ar = srow < mrem ? srow : (mrem - 1);
    int tok = row_tok[row0 + ar];
    const float* ap = x + (size_t)tok * DD + shalf;
    int n0 = blockIdx.y * 128;
    const unsigned short* bp = w1t + (size_t)e * HH * DD + (size_t)(n0 + srow) * DD + shalf;

    floatx4 acc[4][4];
#pragma unroll
    for (int i = 0; i < 4; i++)
#pragma unroll
        for (int j = 0; j < 4; j++)
#pragma unroll
            for (int r = 0; r < 4; r++) acc[i][j][r] = 0.f;

    for (int kt = 0; kt < DD / 32; kt++) {
        int k0 = kt * 32;
        // stage A (fp32 -> bf16)
        alignas(16) unsigned short tmp[16];
        const float4* apv = (const float4*)(ap + k0);
#pragma unroll
        for (int j = 0; j < 4; j++) {
            float4 v = apv[j];
            tmp[4*j+0] = f2bf(v.x); tmp[4*j+1] = f2bf(v.y);
            tmp[4*j+2] = f2bf(v.z); tmp[4*j+3] = f2bf(v.w);
        }
        *(uint4*)&As[srow][shalf]     = *(uint4*)&tmp[0];
        *(uint4*)&As[srow][shalf + 8] = *(uint4*)&tmp[8];
        // stage B (already bf16)
        uint4 b0 = *(const uint4*)(bp + k0);
        uint4 b1 = *(const uint4*)(bp + k0 + 8);
        *(uint4*)&Bs[srow][shalf]     = b0;
        *(uint4*)&Bs[srow][shalf + 8] = b1;
        __syncthreads();

        short8 afr[4], bfr[4];
#pragma unroll
        for (int fm = 0; fm < 4; fm++) afr[fm] = *(const short8*)&As[wm + fm*16 + l15][quad * 8];
#pragma unroll
        for (int fn = 0; fn < 4; fn++) bfr[fn] = *(const short8*)&Bs[wn + fn*16 + l15][quad * 8];
#pragma unroll
        for (int fm = 0; fm < 4; fm++)
#pragma unroll
            for (int fn = 0; fn < 4; fn++)
                acc[fm][fn] = __builtin_amdgcn_mfma_f32_16x16x32_bf16(afr[fm], bfr[fn], acc[fm][fn], 0, 0, 0);
        __syncthreads();
    }

#pragma unroll
    for (int fm = 0; fm < 4; fm++)
#pragma unroll
        for (int r = 0; r < 4; r++) {
            int rt = wm + fm * 16 + quad * 4 + r;
            if (rt < mrem) {
                size_t hrow = (size_t)(row0 + rt) * HH;
#pragma unroll
                for (int fn = 0; fn < 4; fn++) {
                    int col = n0 + wn + fn * 16 + l15;
                    float v = acc[fm][fn][r];
                    float g = 0.5f * v * (1.f + erff(v * 0.70710678118654752f));
                    h[hrow + col] = f2bf(g);
                }
            }
        }
}

// ---------------------------------------------------------------------------
// 6. GEMM2: y = h @ W2[e], out[token] += gate * y   (M=cnt_e, K=3072, N=768)
// ---------------------------------------------------------------------------
__global__ __launch_bounds__(256, 2) void gemm2_kernel(
    const unsigned short* __restrict__ h, const unsigned short* __restrict__ w2t,
    float* __restrict__ out, const int* __restrict__ offs,
    const int* __restrict__ row_tok, const float* __restrict__ row_gate)
{
    int e = blockIdx.x >> 4, mt = blockIdx.x & 15;
    int base = offs[e], cnt = offs[e + 1] - base;
    if (mt * 128 >= cnt) return;
    int row0 = base + mt * 128;
    int mrem = cnt - mt * 128; if (mrem > 128) mrem = 128;

    __shared__ alignas(16) unsigned short As[128][40];
    __shared__ alignas(16) unsigned short Bs[128][40];

    int tid = threadIdx.x;
    int wave = tid >> 6, lane = tid & 63;
    int quad = lane >> 4, l15 = lane & 15;
    int wm = (wave & 1) * 64, wn = (wave >> 1) * 64;
    int srow = tid >> 1, shalf = (tid & 1) * 16;

    int ar = srow < mrem ? srow : (mrem - 1);
    const unsigned short* ap = h + (size_t)(row0 + ar) * HH + shalf;
    int n0 = blockIdx.y * 128;
    const unsigned short* bp = w2t + (size_t)e * DD * HH + (size_t)(n0 + srow) * HH + shalf;

    floatx4 acc[4][4];
#pragma unroll
    for (int i = 0; i < 4; i++)
#pragma unroll
        for (int j = 0; j < 4; j++)
#pragma unroll
            for (int r = 0; r < 4; r++) acc[i][j][r] = 0.f;

    for (int kt = 0; kt < HH / 32; kt++) {
        int k0 = kt * 32;
        uint4 a0 = *(const uint4*)(ap + k0);
        uint4 a1 = *(const uint4*)(ap + k0 + 8);
        uint4 b0 = *(const uint4*)(bp + k0);
        uint4 b1 = *(const uint4*)(bp + k0 + 8);
        *(uint4*)&As[srow][shalf]     = a0;
        *(uint4*)&As[srow][shalf + 8] = a1;
        *(uint4*)&Bs[srow][shalf]     = b0;
        *(uint4*)&Bs[srow][shalf + 8] = b1;
        __syncthreads();

        short8 afr[4], bfr[4];
#pragma unroll
        for (int fm = 0; fm < 4; fm++) afr[fm] = *(const short8*)&As[wm + fm*16 + l15][quad * 8];
#pragma unroll
        for (int fn = 0; fn < 4; fn++) bfr[fn] = *(const short8*)&Bs[wn + fn*16 + l15][quad * 8];
#pragma unroll
        for (int fm = 0; fm < 4; fm++)
#pragma unroll
            for (int fn = 0; fn < 4; fn++)
                acc[fm][fn] = __builtin_amdgcn_mfma_f32_16x16x32_bf16(afr[fm], bfr[fn], acc[fm][fn], 0, 0, 0);
        __syncthreads();
    }

#pragma unroll
    for (int fm = 0; fm < 4; fm++)
#pragma unroll
        for (int r = 0; r < 4; r++) {
            int rt = wm + fm * 16 + quad * 4 + r;
            if (rt < mrem) {
                int gr = row0 + rt;
                int tokn = row_tok[gr];
                float gate = row_gate[gr];
                float* op = out + (size_t)tokn * DD;
#pragma unroll
                for (int fn = 0; fn < 4; fn++) {
                    int col = n0 + wn + fn * 16 + l15;
                    atomicAdd(&op[col], gate * acc[fm][fn][r]);
                }
            }
        }
}

// ---------------------------------------------------------------------------
extern "C" void kernel_launch(void* const* d_in, const int* in_sizes, int n_in,
                              void* d_out, int out_size, void* d_ws, size_t ws_size,
                              hipStream_t stream)
{
    const float* x  = (const float*)d_in[0];
    const float* Wr = (const float*)d_in[1];
    const float* W1 = (const float*)d_in[2];
    const float* W2 = (const float*)d_in[3];
    float* out = (float*)d_out;

    char* ws = (char*)d_ws;
    int*   counts   = (int*)(ws + 0);          // 8 ints (also cursor)
    float* psum     = (float*)(ws + 32);       // 8 floats
    int*   offs     = (int*)(ws + 64);         // 9 ints
    int*   top_e    = (int*)(ws + 128);
    float* top_g    = (float*)(ws + 128 + 16384);
    int*   row_tok  = (int*)(ws + 128 + 2 * 16384);
    float* row_gate = (float*)(ws + 128 + 3 * 16384);
    size_t off = (128 + 4 * 16384 + 255) & ~(size_t)255;
    unsigned short* hbuf = (unsigned short*)(ws + off); off += (size_t)MM * HH * 2;
    unsigned short* w1t  = (unsigned short*)(ws + off); off += (size_t)EE * DD * HH * 2;
    unsigned short* w2t  = (unsigned short*)(ws + off);

    hipMemsetAsync(d_out, 0, (size_t)(NN * DD + 1) * sizeof(float), stream);
    hipMemsetAsync(ws, 0, 64, stream);

    transpose_cast_kernel<<<dim3(576, EE, 2), 256, 0, stream>>>(W1, W2, w1t, w2t);
    routing_kernel<<<dim3(NN / 256), 256, 0, stream>>>(x, Wr, counts, psum, top_e, top_g);
    scan_aux_kernel<<<1, 64, 0, stream>>>(counts, psum, offs, out + (size_t)NN * DD);
    scatter_kernel<<<dim3(NN / 256), 256, 0, stream>>>(top_e, top_g, counts, row_tok, row_gate);
    gemm1_kernel<<<dim3(EE * 16, HH / 128), 256, 0, stream>>>(x, w1t, hbuf, offs, row_tok);
    gemm2_kernel<<<dim3(EE * 16, DD / 128), 256, 0, stream>>>(hbuf, w2t, out, offs, row_tok, row_gate);
}

// Round 2
// 471.550 us; speedup vs baseline: 1.1475x; 1.1475x over previous
//
#include <hip/hip_runtime.h>
#include <hip/hip_bf16.h>
#include <math.h>

#define DD 768
#define HH 3072
#define EE 8
#define NN 2048   // B*T tokens
#define PP 5120   // max padded compact rows (4096 + 8*128)
#define PT 40     // max padded m-tiles (PP/128)

typedef __attribute__((ext_vector_type(8))) short short8;   // 8 bf16 MFMA operand
typedef __attribute__((ext_vector_type(4))) float floatx4;  // MFMA accumulator

typedef const __attribute__((address_space(1))) void gas_void;
typedef __attribute__((address_space(3))) void las_void;

__device__ __forceinline__ void gld16(const void* g, void* l) {
    // async global->LDS DMA, 16B/lane; LDS dest = wave-uniform base + lane*16
    __builtin_amdgcn_global_load_lds((gas_void*)g, (las_void*)l, 16, 0, 0);
}

__device__ __forceinline__ unsigned short f2bf(float f) {
    union { float f; unsigned int u; } v; v.f = f;
    unsigned int u = v.u;
    u += 0x7fffu + ((u >> 16) & 1u);   // RNE (inputs finite)
    return (unsigned short)(u >> 16);
}

// ---------------------------------------------------------------------------
// 1. Routing: z3 = x.Wr^T ; logits = z3.dirs^T ; softmax ; top-2 ; gates
// ---------------------------------------------------------------------------
__global__ __launch_bounds__(256) void routing_kernel(
    const float* __restrict__ x, const float* __restrict__ Wr,
    int* __restrict__ counts, float* __restrict__ psum,
    int* __restrict__ top_e, float* __restrict__ top_g)
{
    __shared__ float wr[3 * DD];
    __shared__ float lpsum[EE];
    int tid = threadIdx.x;
    for (int i = tid; i < 3 * DD; i += 256) wr[i] = Wr[i];
    if (tid < EE) lpsum[tid] = 0.f;
    __syncthreads();

    int n = blockIdx.x * 256 + tid;
    const float4* xp = (const float4*)(x + (size_t)n * DD);
    float z0 = 0.f, z1 = 0.f, z2 = 0.f;
#pragma unroll 8
    for (int i = 0; i < DD / 4; i++) {
        float4 v = xp[i];
        int d = i * 4;
        z0 = fmaf(v.x, wr[d], z0);         z0 = fmaf(v.y, wr[d+1], z0);
        z0 = fmaf(v.z, wr[d+2], z0);       z0 = fmaf(v.w, wr[d+3], z0);
        z1 = fmaf(v.x, wr[DD+d], z1);      z1 = fmaf(v.y, wr[DD+d+1], z1);
        z1 = fmaf(v.z, wr[DD+d+2], z1);    z1 = fmaf(v.w, wr[DD+d+3], z1);
        z2 = fmaf(v.x, wr[2*DD+d], z2);    z2 = fmaf(v.y, wr[2*DD+d+1], z2);
        z2 = fmaf(v.z, wr[2*DD+d+2], z2);  z2 = fmaf(v.w, wr[2*DD+d+3], z2);
    }

    const float r3 = 0.57735026918962576f; // 1/sqrt(3)
    float p[EE];
    float mx = -1e30f;
#pragma unroll
    for (int e = 0; e < EE; e++) {
        float s0 = (e & 4) ? z0 : -z0;   // itertools.product([-1,1]) order
        float s1 = (e & 2) ? z1 : -z1;
        float s2 = (e & 1) ? z2 : -z2;
        p[e] = (s0 + s1 + s2) * r3;
        mx = fmaxf(mx, p[e]);
    }
    float sum = 0.f;
#pragma unroll
    for (int e = 0; e < EE; e++) { p[e] = expf(p[e] - mx); sum += p[e]; }
    float inv_s = 1.f / sum;
#pragma unroll
    for (int e = 0; e < EE; e++) p[e] *= inv_s;

    int e1 = 0; float p1 = p[0];
#pragma unroll
    for (int e = 1; e < EE; e++) if (p[e] > p1) { p1 = p[e]; e1 = e; }
    int e2 = -1; float p2 = -1.f;
#pragma unroll
    for (int e = 0; e < EE; e++) if (e != e1 && p[e] > p2) { p2 = p[e]; e2 = e; }
    float inv_t = 1.f / (p1 + p2);
    top_e[2*n]   = e1;  top_g[2*n]   = p1 * inv_t;
    top_e[2*n+1] = e2;  top_g[2*n+1] = p2 * inv_t;
    atomicAdd(&counts[e1], 1);
    atomicAdd(&counts[e2], 1);

#pragma unroll
    for (int e = 0; e < EE; e++) atomicAdd(&lpsum[e], p[e]);
    __syncthreads();
    if (tid < EE) atomicAdd(&psum[tid], lpsum[tid]);
}

// ---------------------------------------------------------------------------
// 2. Scan counts -> padded offsets (128-aligned), cursor, aux loss
// ---------------------------------------------------------------------------
__global__ void scan_aux_kernel(const int* __restrict__ counts, const float* __restrict__ psum,
                                int* __restrict__ cursor, int* __restrict__ poffs,
                                float* __restrict__ out_aux)
{
    if (threadIdx.x == 0) {
        int run = 0;
        for (int e = 0; e < EE; e++) {
            poffs[e] = run;
            cursor[e] = run;
            run += ((counts[e] + 127) >> 7) << 7;   // pad each expert to 128
        }
        poffs[EE] = run;
        float s = 0.f;
        for (int e = 0; e < EE; e++) {
            float t = psum[e] * (1.f / NN) - (1.f / EE);
            s += t * t;
        }
        *out_aux = 0.01f * (s * (1.f / EE));
    }
}

// ---------------------------------------------------------------------------
// 3. Scatter tokens into padded compact per-expert rows
// ---------------------------------------------------------------------------
__global__ __launch_bounds__(256) void scatter_kernel(
    const int* __restrict__ top_e, const float* __restrict__ top_g,
    int* __restrict__ cursor, int* __restrict__ row_tok, float* __restrict__ row_gate)
{
    int n = blockIdx.x * 256 + threadIdx.x;
#pragma unroll
    for (int k = 0; k < 2; k++) {
        int e = top_e[2*n + k];
        int pos = atomicAdd(&cursor[e], 1);
        row_tok[pos]  = n;
        row_gate[pos] = top_g[2*n + k];
    }
}

// ---------------------------------------------------------------------------
// 3b. Gather+cast: xg[pr] = bf16(x[row_tok[pr]]); zero pad rows, gate=0
// ---------------------------------------------------------------------------
__global__ __launch_bounds__(192) void gather_cast_kernel(
    const float* __restrict__ x, const int* __restrict__ counts,
    const int* __restrict__ poffs, int* __restrict__ row_tok,
    float* __restrict__ row_gate, unsigned short* __restrict__ xg)
{
    int t = threadIdx.x;
    int pr = blockIdx.x * 4 + t / 48;      // 4 rows / block, 48 threads / row
    int c0 = (t % 48) * 16;                // 16 elements / thread
    int e = 0;
#pragma unroll
    for (int i = 0; i < EE - 1; i++) if (pr >= poffs[i + 1]) e = i + 1;
    int local = pr - poffs[e];
    unsigned short* dst = xg + (size_t)pr * DD + c0;
    if (local < counts[e]) {
        int tok = row_tok[pr];
        const float4* sp = (const float4*)(x + (size_t)tok * DD + c0);
        alignas(16) unsigned short tmp[16];
#pragma unroll
        for (int j = 0; j < 4; j++) {
            float4 v = sp[j];
            tmp[4*j+0] = f2bf(v.x); tmp[4*j+1] = f2bf(v.y);
            tmp[4*j+2] = f2bf(v.z); tmp[4*j+3] = f2bf(v.w);
        }
        *(uint4*)dst       = *(uint4*)&tmp[0];
        *(uint4*)(dst + 8) = *(uint4*)&tmp[8];
    } else {
        uint4 z = {0, 0, 0, 0};
        *(uint4*)dst       = z;
        *(uint4*)(dst + 8) = z;
        if (c0 == 0) { row_tok[pr] = 0; row_gate[pr] = 0.f; }
    }
}

// ---------------------------------------------------------------------------
// 4. Weight transpose + bf16 cast: W1(E,D,H)->w1t(E,H,D), W2(E,H,D)->w2t(E,D,H)
// ---------------------------------------------------------------------------
__global__ __launch_bounds__(256) void transpose_cast_kernel(
    const float* __restrict__ W1, const float* __restrict__ W2,
    unsigned short* __restrict__ w1t, unsigned short* __restrict__ w2t)
{
    int z = blockIdx.z, e = blockIdx.y, bx = blockIdx.x;
    const float* src; unsigned short* dst; int R, C, rt, ct;
    if (z == 0) { R = DD; C = HH; src = W1 + (size_t)e * R * C; dst = w1t + (size_t)e * R * C; }
    else        { R = HH; C = DD; src = W2 + (size_t)e * R * C; dst = w2t + (size_t)e * R * C; }
    rt = bx / (C / 64); ct = bx % (C / 64);
    int r0 = rt * 64, c0 = ct * 64;

    __shared__ unsigned short tile[64][66];
    int tid = threadIdx.x;
    int lr = tid >> 2, lc = (tid & 3) * 16;
    const float4* sp = (const float4*)(src + (size_t)(r0 + lr) * C + c0 + lc);
#pragma unroll
    for (int j = 0; j < 4; j++) {
        float4 v = sp[j];
        tile[lr][lc + 4*j + 0] = f2bf(v.x);
        tile[lr][lc + 4*j + 1] = f2bf(v.y);
        tile[lr][lc + 4*j + 2] = f2bf(v.z);
        tile[lr][lc + 4*j + 3] = f2bf(v.w);
    }
    __syncthreads();
    int oc = tid >> 2, orr = (tid & 3) * 16;
    alignas(16) unsigned short tmp[16];
#pragma unroll
    for (int j = 0; j < 16; j++) tmp[j] = tile[orr + j][oc];
    unsigned short* dp = dst + (size_t)(c0 + oc) * R + r0 + orr;
    *(uint4*)dp       = *(uint4*)&tmp[0];
    *(uint4*)(dp + 8) = *(uint4*)&tmp[8];
}

// ---------------------------------------------------------------------------
// 5. GEMM1: h = gelu(xg @ W1[e]^T-layout) -> bf16. m97 structure:
//    global_load_lds width-16 staging into [128][32] LDS, 2-barrier K-loop.
// ---------------------------------------------------------------------------
__global__ __launch_bounds__(256) void gemm1_kernel(
    const unsigned short* __restrict__ xg, const unsigned short* __restrict__ w1t,
    unsigned short* __restrict__ h, const int* __restrict__ poffs)
{
    int t = blockIdx.x;
    if (t * 128 >= poffs[EE]) return;
    int e = 0;
#pragma unroll
    for (int i = 0; i < EE - 1; i++) if (t * 128 >= poffs[i + 1]) e = i + 1;
    int row0 = t * 128, n0 = blockIdx.y * 128;

    __shared__ alignas(16) unsigned short As[128][32];
    __shared__ alignas(16) unsigned short Bs[128][32];

    int tid = threadIdx.x;
    int w = tid >> 6, lane = tid & 63;
    int quad = lane >> 4, l15 = lane & 15;
    int wm = (w & 1) * 64, wn = (w >> 1) * 64;

    const unsigned short* abase = xg + (size_t)row0 * DD;
    const unsigned short* bbase = w1t + (size_t)e * HH * DD + (size_t)n0 * DD;

    // chunk c covers shorts [c*8, c*8+8): row = c>>2, k-part = (c&3)*8
    int c0 = w * 64 + lane, c1 = 256 + c0;
    const unsigned short* ga0 = abase + (c0 >> 2) * DD + (c0 & 3) * 8;
    const unsigned short* ga1 = abase + (c1 >> 2) * DD + (c1 & 3) * 8;
    const unsigned short* gb0 = bbase + (c0 >> 2) * DD + (c0 & 3) * 8;
    const unsigned short* gb1 = bbase + (c1 >> 2) * DD + (c1 & 3) * 8;
    unsigned short* lA0 = &As[0][0] + (w * 64) * 8;          // wave-uniform bases
    unsigned short* lA1 = &As[0][0] + (256 + w * 64) * 8;
    unsigned short* lB0 = &Bs[0][0] + (w * 64) * 8;
    unsigned short* lB1 = &Bs[0][0] + (256 + w * 64) * 8;

    floatx4 acc[4][4];
#pragma unroll
    for (int i = 0; i < 4; i++)
#pragma unroll
        for (int j = 0; j < 4; j++)
#pragma unroll
            for (int r = 0; r < 4; r++) acc[i][j][r] = 0.f;

    for (int kt = 0; kt < DD / 32; kt++) {
        int k0 = kt * 32;
        gld16(ga0 + k0, lA0);
        gld16(ga1 + k0, lA1);
        gld16(gb0 + k0, lB0);
        gld16(gb1 + k0, lB1);
        __syncthreads();

        short8 afr[4], bfr[4];
#pragma unroll
        for (int fm = 0; fm < 4; fm++) afr[fm] = *(const short8*)&As[wm + fm*16 + l15][quad * 8];
#pragma unroll
        for (int fn = 0; fn < 4; fn++) bfr[fn] = *(const short8*)&Bs[wn + fn*16 + l15][quad * 8];
#pragma unroll
        for (int fm = 0; fm < 4; fm++)
#pragma unroll
            for (int fn = 0; fn < 4; fn++)
                acc[fm][fn] = __builtin_amdgcn_mfma_f32_16x16x32_bf16(afr[fm], bfr[fn], acc[fm][fn], 0, 0, 0);
        __syncthreads();
    }

#pragma unroll
    for (int fm = 0; fm < 4; fm++)
#pragma unroll
        for (int r = 0; r < 4; r++) {
            int rt = wm + fm * 16 + quad * 4 + r;
            size_t hrow = (size_t)(row0 + rt) * HH;
#pragma unroll
            for (int fn = 0; fn < 4; fn++) {
                int col = n0 + wn + fn * 16 + l15;
                float v = acc[fm][fn][r];
                float g = 0.5f * v * (1.f + erff(v * 0.70710678118654752f));
                h[hrow + col] = f2bf(g);
            }
        }
}

// ---------------------------------------------------------------------------
// 6. GEMM2: y = h @ W2[e], out[token] += gate * y. K split in 2 for occupancy.
// ---------------------------------------------------------------------------
__global__ __launch_bounds__(256) void gemm2_kernel(
    const unsigned short* __restrict__ h, const unsigned short* __restrict__ w2t,
    float* __restrict__ out, const int* __restrict__ poffs,
    const int* __restrict__ row_tok, const float* __restrict__ row_gate)
{
    int t = blockIdx.x;
    if (t * 128 >= poffs[EE]) return;
    int e = 0;
#pragma unroll
    for (int i = 0; i < EE - 1; i++) if (t * 128 >= poffs[i + 1]) e = i + 1;
    int row0 = t * 128, n0 = blockIdx.y * 128;
    int kz = blockIdx.z;                  // K-split: [kz*1536, kz*1536+1536)

    __shared__ alignas(16) unsigned short As[128][32];
    __shared__ alignas(16) unsigned short Bs[128][32];

    int tid = threadIdx.x;
    int w = tid >> 6, lane = tid & 63;
    int quad = lane >> 4, l15 = lane & 15;
    int wm = (w & 1) * 64, wn = (w >> 1) * 64;

    const unsigned short* abase = h + (size_t)row0 * HH + kz * (HH / 2);
    const unsigned short* bbase = w2t + (size_t)e * DD * HH + (size_t)n0 * HH + kz * (HH / 2);

    int c0 = w * 64 + lane, c1 = 256 + c0;
    const unsigned short* ga0 = abase + (c0 >> 2) * HH + (c0 & 3) * 8;
    const unsigned short* ga1 = abase + (c1 >> 2) * HH + (c1 & 3) * 8;
    const unsigned short* gb0 = bbase + (c0 >> 2) * HH + (c0 & 3) * 8;
    const unsigned short* gb1 = bbase + (c1 >> 2) * HH + (c1 & 3) * 8;
    unsigned short* lA0 = &As[0][0] + (w * 64) * 8;
    unsigned short* lA1 = &As[0][0] + (256 + w * 64) * 8;
    unsigned short* lB0 = &Bs[0][0] + (w * 64) * 8;
    unsigned short* lB1 = &Bs[0][0] + (256 + w * 64) * 8;

    floatx4 acc[4][4];
#pragma unroll
    for (int i = 0; i < 4; i++)
#pragma unroll
        for (int j = 0; j < 4; j++)
#pragma unroll
            for (int r = 0; r < 4; r++) acc[i][j][r] = 0.f;

    for (int kt = 0; kt < (HH / 2) / 32; kt++) {
        int k0 = kt * 32;
        gld16(ga0 + k0, lA0);
        gld16(ga1 + k0, lA1);
        gld16(gb0 + k0, lB0);
        gld16(gb1 + k0, lB1);
        __syncthreads();

        short8 afr[4], bfr[4];
#pragma unroll
        for (int fm = 0; fm < 4; fm++) afr[fm] = *(const short8*)&As[wm + fm*16 + l15][quad * 8];
#pragma unroll
        for (int fn = 0; fn < 4; fn++) bfr[fn] = *(const short8*)&Bs[wn + fn*16 + l15][quad * 8];
#pragma unroll
        for (int fm = 0; fm < 4; fm++)
#pragma unroll
            for (int fn = 0; fn < 4; fn++)
                acc[fm][fn] = __builtin_amdgcn_mfma_f32_16x16x32_bf16(afr[fm], bfr[fn], acc[fm][fn], 0, 0, 0);
        __syncthreads();
    }

#pragma unroll
    for (int fm = 0; fm < 4; fm++)
#pragma unroll
        for (int r = 0; r < 4; r++) {
            int rt = wm + fm * 16 + quad * 4 + r;
            int gr = row0 + rt;
            int tokn = row_tok[gr];
            float gate = row_gate[gr];          // 0 for pad rows -> adds 0
            float* op = out + (size_t)tokn * DD;
#pragma unroll
            for (int fn = 0; fn < 4; fn++) {
                int col = n0 + wn + fn * 16 + l15;
                atomicAdd(&op[col], gate * acc[fm][fn][r]);
            }
        }
}

// ---------------------------------------------------------------------------
extern "C" void kernel_launch(void* const* d_in, const int* in_sizes, int n_in,
                              void* d_out, int out_size, void* d_ws, size_t ws_size,
                              hipStream_t stream)
{
    const float* x  = (const float*)d_in[0];
    const float* Wr = (const float*)d_in[1];
    const float* W1 = (const float*)d_in[2];
    const float* W2 = (const float*)d_in[3];
    float* out = (float*)d_out;

    char* ws = (char*)d_ws;
    int*   counts   = (int*)(ws + 0);        // 8
    int*   cursor   = (int*)(ws + 32);       // 8
    float* psum     = (float*)(ws + 64);     // 8
    int*   poffs    = (int*)(ws + 96);       // 9
    int*   top_e    = (int*)(ws + 1024);                 // 4096 ints
    float* top_g    = (float*)(ws + 1024 + 16384);       // 4096 floats
    int*   row_tok  = (int*)(ws + 1024 + 2 * 16384);     // PP ints
    float* row_gate = (float*)(ws + 1024 + 2 * 16384 + PP * 4);
    size_t off = (size_t)(1024 + 2 * 16384 + 2 * PP * 4 + 255) & ~(size_t)255;
    unsigned short* xg  = (unsigned short*)(ws + off); off += (size_t)PP * DD * 2;
    unsigned short* hbf = (unsigned short*)(ws + off); off += (size_t)PP * HH * 2;
    unsigned short* w1t = (unsigned short*)(ws + off); off += (size_t)EE * DD * HH * 2;
    unsigned short* w2t = (unsigned short*)(ws + off);

    hipMemsetAsync(d_out, 0, (size_t)(NN * DD + 1) * sizeof(float), stream);
    hipMemsetAsync(ws, 0, 96, stream);   // counts + cursor + psum

    transpose_cast_kernel<<<dim3(576, EE, 2), 256, 0, stream>>>(W1, W2, w1t, w2t);
    routing_kernel<<<dim3(NN / 256), 256, 0, stream>>>(x, Wr, counts, psum, top_e, top_g);
    scan_aux_kernel<<<1, 64, 0, stream>>>(counts, psum, cursor, poffs, out + (size_t)NN * DD);
    scatter_kernel<<<dim3(NN / 256), 256, 0, stream>>>(top_e, top_g, cursor, row_tok, row_gate);
    gather_cast_kernel<<<dim3(PP / 4), 192, 0, stream>>>(x, counts, poffs, row_tok, row_gate, xg);
    gemm1_kernel<<<dim3(PT, HH / 128), 256, 0, stream>>>(xg, w1t, hbf, poffs);
    gemm2_kernel<<<dim3(PT, DD / 128, 2), 256, 0, stream>>>(hbf, w2t, out, poffs, row_tok, row_gate);
}